// Round 18
// baseline (33.270 us; speedup 1.0000x reference)
//
#include <hip/hip_runtime.h>
#include <math.h>

typedef _Float16 f16x8 __attribute__((ext_vector_type(8)));
typedef float f32x16 __attribute__((ext_vector_type(16)));

#define TILE 1024  // refs per block: 1024 * 32B = 32 KB LDS, 4 blocks/CU

__device__ __forceinline__ float decode_scalar(const int* p) {
    int i = *p;
    if (i > -16777216 && i < 16777216) return (float)i;
    return __int_as_float(i);
}
__device__ __forceinline__ float min3f(float a, float b, float c) {
    float d;
    asm("v_min3_f32 %0, %1, %2, %3" : "=v"(d) : "v"(a), "v"(b), "v"(c));
    return d;
}

// K=16 encoding, a = -2*pt, hi/lo f16 split, rn = |pt|^2:
//  A (query): [ah3, al3, ah3, al3, qnh, qnl, 1, 1]   (half 0 = k0-7, half 1 = k8-15)
//  B (ref)  : [bh3, bh3, bl3, bl3, 1, 1, rnh, rnl]
//  sum_k A_k B_k = (ah+al)·(bh+bl) + qn + rn = ||q-r||^2 (exact to ~fp32)
__device__ __forceinline__ f16x8 make_afrag(float x, float y, float z, int half) {
    const float rn = fmaf(x, x, fmaf(y, y, z * z));
    const float ax = -2.f * x, ay = -2.f * y, az = -2.f * z;
    const _Float16 ahx = (_Float16)ax, ahy = (_Float16)ay, ahz = (_Float16)az;
    const _Float16 alx = (_Float16)(ax - (float)ahx);
    const _Float16 aly = (_Float16)(ay - (float)ahy);
    const _Float16 alz = (_Float16)(az - (float)ahz);
    const _Float16 rh = (_Float16)rn, rl = (_Float16)(rn - (float)rh);
    const _Float16 one = (_Float16)1.f;
    if (half == 0) return (f16x8){ahx, ahy, ahz, alx, aly, alz, ahx, ahy};
    return (f16x8){ahz, alx, aly, alz, rh, rl, one, one};
}
__device__ __forceinline__ void make_bfrags(float x, float y, float z,
                                            f16x8* b0, f16x8* b1) {
    const float rn = fmaf(x, x, fmaf(y, y, z * z));
    const _Float16 bhx = (_Float16)x, bhy = (_Float16)y, bhz = (_Float16)z;
    const _Float16 blx = (_Float16)(x - (float)bhx);
    const _Float16 bly = (_Float16)(y - (float)bhy);
    const _Float16 blz = (_Float16)(z - (float)bhz);
    const _Float16 rh = (_Float16)rn, rl = (_Float16)(rn - (float)rh);
    const _Float16 one = (_Float16)1.f;
    *b0 = (f16x8){bhx, bhy, bhz, bhx, bhy, bhz, blx, bly};
    *b1 = (f16x8){blz, blx, bly, blz, one, one, rh, rl};
}

// Stage 1: 32x32x16 MFMA distance tiles, running column-min in registers.
// R18: __launch_bounds__(256,4) caps VGPR at 128 -> 4 waves/SIMD resident.
// (R14 measured 985cyc/iter serial; R16/17's 26us = 488cyc/iter = only 2x
// overlap -> residency, not pipes, is the wall. Live set ~110-120 fits 128.)
__global__ __launch_bounds__(256, 4) void nn_mfma(
    const float* __restrict__ preds, const float* __restrict__ gts,
    int M, int N, int B, int rsplit, int Qstride, float* __restrict__ part)
{
    const int zc    = blockIdx.z;
    const int dir   = zc / rsplit;       // 0: q=preds ref=gts ; 1: q=gts ref=preds
    const int chunk = zc - dir * rsplit;
    const int b     = blockIdx.y;

    const int Q = dir ? N : M;
    const int R = dir ? M : N;
    const float* __restrict__ qraw = (dir ? gts : preds) + (size_t)b * Q * 3;
    const float* __restrict__ rraw = (dir ? preds : gts) + (size_t)b * R * 3;

    const int q0blk = blockIdx.x * 256;
    if (q0blk >= Q) return;
    const int tid  = threadIdx.x;
    const int lane = tid & 63, w = tid >> 6;
    const int q0   = q0blk + w * 64;            // wave owns queries q0..q0+63
    const int lrow = lane & 31, lh = lane >> 5; // A row / k-half

    float ax = 0.f, ay = 0.f, az = 0.f, bx = 0.f, by = 0.f, bz = 0.f;
    const int qa = q0 + lrow, qb = q0 + 32 + lrow;
    if (qa < Q) { const float* s = qraw + (size_t)qa * 3; ax = s[0]; ay = s[1]; az = s[2]; }
    if (qb < Q) { const float* s = qraw + (size_t)qb * 3; bx = s[0]; by = s[1]; bz = s[2]; }
    const f16x8 af0 = make_afrag(ax, ay, az, lh);
    const f16x8 af1 = make_afrag(bx, by, bz, lh);

    __shared__ f16x8 sB[TILE * 2];   // 32 KB; reused as 4 x 8KB transpose pads

    f32x16 rm0, rm1;
    #pragma unroll
    for (int j = 0; j < 16; ++j) { rm0[j] = INFINITY; rm1[j] = INFINITY; }

    const int tilesTotal = (R + TILE - 1) / TILE;
    const int tpc = (tilesTotal + rsplit - 1) / rsplit;
    const int t0 = chunk * tpc;
    const int t1 = min(tilesTotal, t0 + tpc);

    for (int tt = t0; tt < t1; ++tt) {
        const int s0 = tt * TILE;
        __syncthreads();
        #pragma unroll
        for (int k = 0; k < 4; ++k) {
            const int p  = tid + k * 256;
            const int gi = s0 + p;
            f16x8 b0, b1;
            if (gi < R) {
                const float* s = rraw + (size_t)gi * 3;
                make_bfrags(s[0], s[1], s[2], &b0, &b1);
            } else {
                const _Float16 z0 = (_Float16)0.f, one = (_Float16)1.f;
                const _Float16 big = (_Float16)60000.f;   // pad -> huge finite dist
                b0 = (f16x8){z0, z0, z0, z0, z0, z0, z0, z0};
                b1 = (f16x8){z0, z0, z0, z0, one, one, big, z0};
            }
            const int g = p >> 5, sl = p & 31;
            sB[g * 64 + sl]      = b0;
            sB[g * 64 + 32 + sl] = b1;
        }
        __syncthreads();

        // per iter: 2 direct ds_read_b128 (contiguous 1KB/wave, conflict-free)
        #pragma unroll 1
        for (int tp = 0; tp < TILE / 64; ++tp) {
            const f16x8 cb0 = sB[2 * tp * 64 + lane];
            const f16x8 cb1 = sB[(2 * tp + 1) * 64 + lane];
            f32x16 dA, dB;
            asm volatile(
                "v_mfma_f32_32x32x16_f16 %0, %2, %3, 0\n\t"
                "v_mfma_f32_32x32x16_f16 %1, %2, %4, 0\n\t"
                "s_nop 7\n\t"
                "s_nop 7\n\t"
                "s_nop 7\n\t"
                "s_nop 7"
                : "=&v"(dA), "=&v"(dB)
                : "v"(af0), "v"(cb0), "v"(cb1));
            #pragma unroll
            for (int j = 0; j < 16; ++j) rm0[j] = min3f(dA[j], dB[j], rm0[j]);
            f32x16 dC, dD;
            asm volatile(
                "v_mfma_f32_32x32x16_f16 %0, %2, %3, 0\n\t"
                "v_mfma_f32_32x32x16_f16 %1, %2, %4, 0\n\t"
                "s_nop 7\n\t"
                "s_nop 7\n\t"
                "s_nop 7\n\t"
                "s_nop 7"
                : "=&v"(dC), "=&v"(dD)
                : "v"(af1), "v"(cb0), "v"(cb1));
            #pragma unroll
            for (int j = 0; j < 16; ++j) rm1[j] = min3f(dC[j], dD[j], rm1[j]);
        }
    }

    // ---- epilogue: LDS transpose, in-lane column-min, coalesced store ----
    __syncthreads();   // all waves done reading sB before overlay writes
    float* sT = (float*)&sB[0] + (w << 11);   // per-wave 2048 floats (8 KB)
    const int c  = lrow;                      // this lane's ref-column
    const int sw = 4 * (c & 7);               // XOR swizzle (16B-preserving)

    // rm0[j] -> query row (j&3)+8*(j>>2)+4*lh ; rm1[j] -> +32. 8x b128 writes.
    #pragma unroll
    for (int jj = 0; jj < 4; ++jj) {
        const int qb0 = jj * 8 + 4 * lh;
        float4 v0 = { rm0[4*jj], rm0[4*jj+1], rm0[4*jj+2], rm0[4*jj+3] };
        *(float4*)&sT[c * 64 + (qb0 ^ sw)] = v0;
        const int qb1 = 32 + qb0;
        float4 v1 = { rm1[4*jj], rm1[4*jj+1], rm1[4*jj+2], rm1[4*jj+3] };
        *(float4*)&sT[c * 64 + (qb1 ^ sw)] = v1;
    }
    __syncthreads();

    // lane owns query q0+lane: gather its 32 column values, min tree
    float t16[16];
    #pragma unroll
    for (int cc = 0; cc < 16; ++cc) {
        const float va = sT[(2*cc)     * 64 + (lane ^ (4 * ((2*cc)     & 7)))];
        const float vb = sT[(2*cc + 1) * 64 + (lane ^ (4 * ((2*cc + 1) & 7)))];
        t16[cc] = fminf(va, vb);
    }
    #pragma unroll
    for (int s = 8; s > 0; s >>= 1)
        #pragma unroll
        for (int i = 0; i < 8; ++i)
            if (i < s) t16[i] = fminf(t16[i], t16[i + s]);

    const size_t pbase = (((size_t)dir * B + b) * rsplit + chunk) * (size_t)Qstride + q0;
    part[pbase + lane] = t16[0];
}

// Stage 2: combine rsplit partial mins, Huber, wave->block reduce, ONE atomic
// per block.
__global__ __launch_bounds__(1024) void huber_reduce(
    const float* __restrict__ part, const int* __restrict__ cptr,
    int M, int N, int B, int rsplit, int Qstride, float* __restrict__ out)
{
    const int dir = blockIdx.z;
    const int b   = blockIdx.y;
    const int Q   = dir ? N : M;
    const int tid = threadIdx.x;
    const int j   = blockIdx.x * 1024 + tid;

    float h = 0.f;
    if (j < Q) {
        const size_t base = (((size_t)dir * B + b) * rsplit) * (size_t)Qstride + j;
        float v = part[base];
        #pragma unroll 4
        for (int k = 1; k < rsplit; ++k) v = fminf(v, part[base + (size_t)k * Qstride]);
        const float c = decode_scalar(cptr);
        h = (v < c) ? (0.5f * v * v) : fmaf(c, v, -0.5f * c * c);
    }

    #pragma unroll
    for (int off = 32; off > 0; off >>= 1) h += __shfl_down(h, off, 64);

    __shared__ float wsum[16];
    if ((tid & 63) == 0) wsum[tid >> 6] = h;
    __syncthreads();
    if (tid < 64) {
        float t = (tid < 16) ? wsum[tid] : 0.f;
        #pragma unroll
        for (int off = 8; off > 0; off >>= 1) t += __shfl_down(t, off, 64);
        if (tid == 0) atomicAdd(out, t);
    }
}

extern "C" void kernel_launch(void* const* d_in, const int* in_sizes, int n_in,
                              void* d_out, int out_size, void* d_ws, size_t ws_size,
                              hipStream_t stream) {
    const float* preds = (const float*)d_in[0];
    const float* gts   = (const float*)d_in[1];
    const int*   cptr  = (const int*)d_in[2];

    const int B = 4, D = 3;
    const int M = in_sizes[0] / (B * D);
    const int N = in_sizes[1] / (B * D);
    const int Qmax = (M > N) ? M : N;
    const int Qstride = (Qmax + 255) & ~255;
    const int rsplit = 4;

    float* part = (float*)d_ws;   // 2*B*rsplit*Qstride floats (1 MB @ 8192)
    hipMemsetAsync(d_out, 0, (size_t)out_size * sizeof(float), stream);

    dim3 g1(Qstride / 256, B, 2 * rsplit);
    nn_mfma<<<g1, 256, 0, stream>>>(preds, gts, M, N, B, rsplit, Qstride, part);

    dim3 g2((Qmax + 1023) / 1024, B, 2);
    huber_reduce<<<g2, 1024, 0, stream>>>(part, cptr, M, N, B, rsplit, Qstride,
                                          (float*)d_out);
}

// Round 19
// 31.416 us; speedup vs baseline: 1.0590x; 1.0590x over previous
//
#include <hip/hip_runtime.h>
#include <math.h>

typedef _Float16 f16x8 __attribute__((ext_vector_type(8)));
typedef float f32x16 __attribute__((ext_vector_type(16)));

#define TILE 1024  // refs per block: 1024 * 32B = 32 KB LDS, 4 blocks/CU

__device__ __forceinline__ float decode_scalar(const int* p) {
    int i = *p;
    if (i > -16777216 && i < 16777216) return (float)i;
    return __int_as_float(i);
}
__device__ __forceinline__ float min3f(float a, float b, float c) {
    float d;
    asm("v_min3_f32 %0, %1, %2, %3" : "=v"(d) : "v"(a), "v"(b), "v"(c));
    return d;
}
#define SBAR() __builtin_amdgcn_sched_barrier(0)

// K=16 encoding, a = -2*pt, hi/lo f16 split, rn = |pt|^2:
//  A (query): [ah3, al3, ah3, al3, qnh, qnl, 1, 1]   (half 0 = k0-7, half 1 = k8-15)
//  B (ref)  : [bh3, bh3, bl3, bl3, 1, 1, rnh, rnl]
//  sum_k A_k B_k = (ah+al)·(bh+bl) + qn + rn = ||q-r||^2 (exact to ~fp32)
__device__ __forceinline__ f16x8 make_afrag(float x, float y, float z, int half) {
    const float rn = fmaf(x, x, fmaf(y, y, z * z));
    const float ax = -2.f * x, ay = -2.f * y, az = -2.f * z;
    const _Float16 ahx = (_Float16)ax, ahy = (_Float16)ay, ahz = (_Float16)az;
    const _Float16 alx = (_Float16)(ax - (float)ahx);
    const _Float16 aly = (_Float16)(ay - (float)ahy);
    const _Float16 alz = (_Float16)(az - (float)ahz);
    const _Float16 rh = (_Float16)rn, rl = (_Float16)(rn - (float)rh);
    const _Float16 one = (_Float16)1.f;
    if (half == 0) return (f16x8){ahx, ahy, ahz, alx, aly, alz, ahx, ahy};
    return (f16x8){ahz, alx, aly, alz, rh, rl, one, one};
}
__device__ __forceinline__ void make_bfrags(float x, float y, float z,
                                            f16x8* b0, f16x8* b1) {
    const float rn = fmaf(x, x, fmaf(y, y, z * z));
    const _Float16 bhx = (_Float16)x, bhy = (_Float16)y, bhz = (_Float16)z;
    const _Float16 blx = (_Float16)(x - (float)bhx);
    const _Float16 bly = (_Float16)(y - (float)bhy);
    const _Float16 blz = (_Float16)(z - (float)bhz);
    const _Float16 rh = (_Float16)rn, rl = (_Float16)(rn - (float)rh);
    const _Float16 one = (_Float16)1.f;
    *b0 = (f16x8){bhx, bhy, bhz, bhx, bhy, bhz, blx, bly};
    *b1 = (f16x8){blz, blx, bly, blz, one, one, rh, rl};
}

// Stage 1: 32x32x16 MFMA distance tiles, running column-min in registers.
// R19: software-pipelined inner loop — fold(prev group) between the two MFMA
// groups provides >=64cyc MFMA->VALU hazard separation, deleting the 8x s_nop 7
// per iter. sched_barrier(0) fences keep hipcc from sinking folds back onto
// their producer MFMA (folds read the PREVIOUS iteration's tiles).
__global__ __launch_bounds__(256) void nn_mfma(
    const float* __restrict__ preds, const float* __restrict__ gts,
    int M, int N, int B, int rsplit, int Qstride, float* __restrict__ part)
{
    const int zc    = blockIdx.z;
    const int dir   = zc / rsplit;       // 0: q=preds ref=gts ; 1: q=gts ref=preds
    const int chunk = zc - dir * rsplit;
    const int b     = blockIdx.y;

    const int Q = dir ? N : M;
    const int R = dir ? M : N;
    const float* __restrict__ qraw = (dir ? gts : preds) + (size_t)b * Q * 3;
    const float* __restrict__ rraw = (dir ? preds : gts) + (size_t)b * R * 3;

    const int q0blk = blockIdx.x * 256;
    if (q0blk >= Q) return;
    const int tid  = threadIdx.x;
    const int lane = tid & 63, w = tid >> 6;
    const int q0   = q0blk + w * 64;            // wave owns queries q0..q0+63
    const int lrow = lane & 31, lh = lane >> 5; // A row / k-half

    float ax = 0.f, ay = 0.f, az = 0.f, bx = 0.f, by = 0.f, bz = 0.f;
    const int qa = q0 + lrow, qb = q0 + 32 + lrow;
    if (qa < Q) { const float* s = qraw + (size_t)qa * 3; ax = s[0]; ay = s[1]; az = s[2]; }
    if (qb < Q) { const float* s = qraw + (size_t)qb * 3; bx = s[0]; by = s[1]; bz = s[2]; }
    const f16x8 af0 = make_afrag(ax, ay, az, lh);
    const f16x8 af1 = make_afrag(bx, by, bz, lh);

    __shared__ f16x8 sB[TILE * 2];   // 32 KB; reused as 4 x 8KB transpose pads

    f32x16 rm0, rm1;
    #pragma unroll
    for (int j = 0; j < 16; ++j) { rm0[j] = INFINITY; rm1[j] = INFINITY; }

    const int tilesTotal = (R + TILE - 1) / TILE;
    const int tpc = (tilesTotal + rsplit - 1) / rsplit;
    const int t0 = chunk * tpc;
    const int t1 = min(tilesTotal, t0 + tpc);

    for (int tt = t0; tt < t1; ++tt) {
        const int s0 = tt * TILE;
        __syncthreads();
        #pragma unroll
        for (int k = 0; k < 4; ++k) {
            const int p  = tid + k * 256;
            const int gi = s0 + p;
            f16x8 b0, b1;
            if (gi < R) {
                const float* s = rraw + (size_t)gi * 3;
                make_bfrags(s[0], s[1], s[2], &b0, &b1);
            } else {
                const _Float16 z0 = (_Float16)0.f, one = (_Float16)1.f;
                const _Float16 big = (_Float16)60000.f;   // pad -> huge finite dist
                b0 = (f16x8){z0, z0, z0, z0, z0, z0, z0, z0};
                b1 = (f16x8){z0, z0, z0, z0, one, one, big, z0};
            }
            const int g = p >> 5, sl = p & 31;
            sB[g * 64 + sl]      = b0;
            sB[g * 64 + 32 + sl] = b1;
        }
        __syncthreads();

        const f16x8* pl = sB + lane;
        // pipeline prologue: iter 0's MFMAs issue, folds deferred
        f16x8 cb0 = pl[0];
        f16x8 cb1 = pl[64];
        f32x16 dA, dB, dC, dD;
        asm volatile(
            "v_mfma_f32_32x32x16_f16 %0, %2, %3, 0\n\t"
            "v_mfma_f32_32x32x16_f16 %1, %2, %4, 0"
            : "=&v"(dA), "=&v"(dB) : "v"(af0), "v"(cb0), "v"(cb1));
        asm volatile(
            "v_mfma_f32_32x32x16_f16 %0, %2, %3, 0\n\t"
            "v_mfma_f32_32x32x16_f16 %1, %2, %4, 0"
            : "=&v"(dC), "=&v"(dD) : "v"(af1), "v"(cb0), "v"(cb1));

        #pragma unroll 1
        for (int tp = 1; tp < TILE / 64; ++tp) {
            SBAR();
            cb0 = pl[tp * 128];
            cb1 = pl[tp * 128 + 64];
            // fold PREVIOUS iter's af0 tiles (written >=64cyc ago: prev asm#2
            // issue + loop overhead provide the MFMA->VALU separation)
            #pragma unroll
            for (int j = 0; j < 16; ++j) rm0[j] = min3f(dA[j], dB[j], rm0[j]);
            SBAR();
            asm volatile(
                "v_mfma_f32_32x32x16_f16 %0, %2, %3, 0\n\t"
                "v_mfma_f32_32x32x16_f16 %1, %2, %4, 0"
                : "=&v"(dA), "=&v"(dB) : "v"(af0), "v"(cb0), "v"(cb1));
            SBAR();
            // fold PREVIOUS iter's af1 tiles (separation: rm0 fold + asm#1)
            #pragma unroll
            for (int j = 0; j < 16; ++j) rm1[j] = min3f(dC[j], dD[j], rm1[j]);
            SBAR();
            asm volatile(
                "v_mfma_f32_32x32x16_f16 %0, %2, %3, 0\n\t"
                "v_mfma_f32_32x32x16_f16 %1, %2, %4, 0"
                : "=&v"(dC), "=&v"(dD) : "v"(af1), "v"(cb0), "v"(cb1));
        }
        SBAR();
        // drain: dA,dB sep = last asm#2 (64cyc) ; dC,dD sep = +32cyc of folds
        #pragma unroll
        for (int j = 0; j < 16; ++j) rm0[j] = min3f(dA[j], dB[j], rm0[j]);
        #pragma unroll
        for (int j = 0; j < 16; ++j) rm1[j] = min3f(dC[j], dD[j], rm1[j]);
    }

    // ---- epilogue: LDS transpose, in-lane column-min, coalesced store ----
    __syncthreads();   // all waves done reading sB before overlay writes
    float* sT = (float*)&sB[0] + (w << 11);   // per-wave 2048 floats (8 KB)
    const int c  = lrow;                      // this lane's ref-column
    const int sw = 4 * (c & 7);               // XOR swizzle (16B-preserving)

    // rm0[j] -> query row (j&3)+8*(j>>2)+4*lh ; rm1[j] -> +32. 8x b128 writes.
    #pragma unroll
    for (int jj = 0; jj < 4; ++jj) {
        const int qb0 = jj * 8 + 4 * lh;
        float4 v0 = { rm0[4*jj], rm0[4*jj+1], rm0[4*jj+2], rm0[4*jj+3] };
        *(float4*)&sT[c * 64 + (qb0 ^ sw)] = v0;
        const int qb1 = 32 + qb0;
        float4 v1 = { rm1[4*jj], rm1[4*jj+1], rm1[4*jj+2], rm1[4*jj+3] };
        *(float4*)&sT[c * 64 + (qb1 ^ sw)] = v1;
    }
    __syncthreads();

    // lane owns query q0+lane: gather its 32 column values, min tree
    float t16[16];
    #pragma unroll
    for (int cc = 0; cc < 16; ++cc) {
        const float va = sT[(2*cc)     * 64 + (lane ^ (4 * ((2*cc)     & 7)))];
        const float vb = sT[(2*cc + 1) * 64 + (lane ^ (4 * ((2*cc + 1) & 7)))];
        t16[cc] = fminf(va, vb);
    }
    #pragma unroll
    for (int s = 8; s > 0; s >>= 1)
        #pragma unroll
        for (int i = 0; i < 8; ++i)
            if (i < s) t16[i] = fminf(t16[i], t16[i + s]);

    const size_t pbase = (((size_t)dir * B + b) * rsplit + chunk) * (size_t)Qstride + q0;
    part[pbase + lane] = t16[0];
}

// Stage 2: combine rsplit partial mins, Huber, wave->block reduce, ONE atomic
// per block.
__global__ __launch_bounds__(1024) void huber_reduce(
    const float* __restrict__ part, const int* __restrict__ cptr,
    int M, int N, int B, int rsplit, int Qstride, float* __restrict__ out)
{
    const int dir = blockIdx.z;
    const int b   = blockIdx.y;
    const int Q   = dir ? N : M;
    const int tid = threadIdx.x;
    const int j   = blockIdx.x * 1024 + tid;

    float h = 0.f;
    if (j < Q) {
        const size_t base = (((size_t)dir * B + b) * rsplit) * (size_t)Qstride + j;
        float v = part[base];
        #pragma unroll 4
        for (int k = 1; k < rsplit; ++k) v = fminf(v, part[base + (size_t)k * Qstride]);
        const float c = decode_scalar(cptr);
        h = (v < c) ? (0.5f * v * v) : fmaf(c, v, -0.5f * c * c);
    }

    #pragma unroll
    for (int off = 32; off > 0; off >>= 1) h += __shfl_down(h, off, 64);

    __shared__ float wsum[16];
    if ((tid & 63) == 0) wsum[tid >> 6] = h;
    __syncthreads();
    if (tid < 64) {
        float t = (tid < 16) ? wsum[tid] : 0.f;
        #pragma unroll
        for (int off = 8; off > 0; off >>= 1) t += __shfl_down(t, off, 64);
        if (tid == 0) atomicAdd(out, t);
    }
}

extern "C" void kernel_launch(void* const* d_in, const int* in_sizes, int n_in,
                              void* d_out, int out_size, void* d_ws, size_t ws_size,
                              hipStream_t stream) {
    const float* preds = (const float*)d_in[0];
    const float* gts   = (const float*)d_in[1];
    const int*   cptr  = (const int*)d_in[2];

    const int B = 4, D = 3;
    const int M = in_sizes[0] / (B * D);
    const int N = in_sizes[1] / (B * D);
    const int Qmax = (M > N) ? M : N;
    const int Qstride = (Qmax + 255) & ~255;
    const int rsplit = 4;

    float* part = (float*)d_ws;   // 2*B*rsplit*Qstride floats (1 MB @ 8192)
    hipMemsetAsync(d_out, 0, (size_t)out_size * sizeof(float), stream);

    dim3 g1(Qstride / 256, B, 2 * rsplit);
    nn_mfma<<<g1, 256, 0, stream>>>(preds, gts, M, N, B, rsplit, Qstride, part);

    dim3 g2((Qmax + 1023) / 1024, B, 2);
    huber_reduce<<<g2, 1024, 0, stream>>>(part, cptr, M, N, B, rsplit, Qstride,
                                          (float*)d_out);
}